// Round 17
// baseline (856.029 us; speedup 1.0000x reference)
//
#include <hip/hip_runtime.h>
#include <math.h>

#define NN 3072
#define FF 256
#define CAPE (1<<18)
#define MAXCH 3200
#define HSZ 2048

struct Scal {
  int nnzS, nnz2, nzero, ncht, ccount;
  int lo, hi, rank_rem, below_acc;
  unsigned prefix, minabove;
  float frac, cut;
};

__device__ __forceinline__ float sigm(float x){ return 1.0f/(1.0f+expf(-x)); }

// ---------------- init: zero bins (once) ----------------
__global__ __launch_bounds__(256) void k_init(unsigned* __restrict__ bins){
  int i=blockIdx.x*256+threadIdx.x;
  if(i<16384) bins[i]=0;
}

// ---------------- CSR build ----------------
__global__ __launch_bounds__(256) void k_count_dense(const float* __restrict__ A, int* __restrict__ rowcnt, float* __restrict__ Drow){
  int i=blockIdx.x, t=threadIdx.x;
  int c=0; float sm=0.f;
  for(int j=t;j<NN;j+=256){ float a=A[(size_t)i*NN+j]; if(a!=0.0f||j==i) c++; sm+=a; }
  __shared__ int s[256]; __shared__ float fs[256];
  s[t]=c; fs[t]=sm; __syncthreads();
  for(int o=128;o;o>>=1){ if(t<o){ s[t]+=s[t+o]; fs[t]+=fs[t+o]; } __syncthreads(); }
  if(t==0){ rowcnt[i]=s[0]; if(Drow) Drow[i]=sqrtf(fs[0]+1.0f); }
}

// scan; also zeroes sc->nzero (consumed later by pick14; re-zero mid-level is harmless)
__global__ __launch_bounds__(1024) void k_scan(const int* __restrict__ cnt, int* __restrict__ rp, int* __restrict__ total, Scal* sc){
  int t=threadIdx.x;
  if(t==0) sc->nzero=0;
  int a0=cnt[t*3+0], a1=cnt[t*3+1], a2=cnt[t*3+2];
  int loc=a0+a1+a2;
  __shared__ int s[1024];
  s[t]=loc; __syncthreads();
  for(int o=1;o<1024;o<<=1){ int v=(t>=o)?s[t-o]:0; __syncthreads(); s[t]+=v; __syncthreads(); }
  int excl=s[t]-loc;
  rp[t*3+0]=excl; rp[t*3+1]=excl+a0; rp[t*3+2]=excl+a0+a1;
  if(t==1023){ rp[NN]=s[t]; *total=s[t]; }
}

// structure = (A!=0) | diag.  acval: from dense ACd (level 0) or (a+I)/(Di*Dj) (levels>=1)
__global__ __launch_bounds__(256) void k_fill_dense(const float* __restrict__ A, const float* __restrict__ ACd, const float* __restrict__ D,
    const int* __restrict__ rp, int* __restrict__ rows, int* __restrict__ cols, float* __restrict__ aval, float* __restrict__ acval){
  int i=blockIdx.x, t=threadIdx.x;
  const int CH=NN/256;
  int j0=t*CH; int c=0;
  for(int u=0;u<CH;u++){ int j=j0+u; float a=A[(size_t)i*NN+j]; if(a!=0.0f||j==i) c++; }
  __shared__ int s[256]; s[t]=c; __syncthreads();
  for(int o=1;o<256;o<<=1){ int v=(t>=o)?s[t-o]:0; __syncthreads(); s[t]+=v; __syncthreads(); }
  int pos=rp[i]+s[t]-c;
  float Di = D?D[i]:0.0f;
  for(int u=0;u<CH;u++){ int j=j0+u; float a=A[(size_t)i*NN+j];
    if(a!=0.0f||j==i){
      if(pos<CAPE){
        rows[pos]=i; cols[pos]=j; aval[pos]=a;
        acval[pos]= ACd? ACd[(size_t)i*NN+j] : (a+(j==i?1.0f:0.0f))/(Di*D[j]);
      }
      pos++;
    }
  }
}

// sparse wipe of dense using the just-built CSR (structure covers all nonzeros)
__global__ __launch_bounds__(256) void k_wipe(const int* __restrict__ rows, const int* __restrict__ cols, const Scal* __restrict__ sc,
    float* __restrict__ dense){
  int e=blockIdx.x*256+threadIdx.x;
  int n=sc->nnzS; if(n>CAPE) n=CAPE;
  if(e<n) dense[(size_t)rows[e]*NN+cols[e]]=0.f;
}

// ---------------- dense GEMM (f32, 64x64 tile, direct store) ----------------
__global__ __launch_bounds__(256) void k_gemm(const float* __restrict__ A, const float* __restrict__ B, float* __restrict__ C,
                                              int M, int K, int Nc){
  __shared__ float As[16][68];
  __shared__ float Bs[16][68];
  int tid=threadIdx.x;
  int tx=tid&15, ty=tid>>4;
  int bm=blockIdx.y*64, bn=blockIdx.x*64;
  int lm=tid>>2, lk=(tid&3)*4;
  int kr=tid>>4, nf=(tid&15)*4;
  float acc[4][4]={};
  for(int k0=0;k0<K;k0+=16){
    float4 a4=*(const float4*)(A+(size_t)(bm+lm)*K+k0+lk);
    As[lk+0][lm]=a4.x; As[lk+1][lm]=a4.y; As[lk+2][lm]=a4.z; As[lk+3][lm]=a4.w;
    float4 b4=*(const float4*)(B+(size_t)(k0+kr)*Nc+bn+nf);
    *(float4*)&Bs[kr][nf]=b4;
    __syncthreads();
#pragma unroll
    for(int kk=0;kk<16;kk++){
      float4 av=*(const float4*)&As[kk][ty*4];
      float4 bv=*(const float4*)&Bs[kk][tx*4];
      float am[4]={av.x,av.y,av.z,av.w};
      float bb[4]={bv.x,bv.y,bv.z,bv.w};
#pragma unroll
      for(int i2=0;i2<4;i2++)
#pragma unroll
        for(int j2=0;j2<4;j2++) acc[i2][j2]+=am[i2]*bb[j2];
    }
    __syncthreads();
  }
  for(int i2=0;i2<4;i2++){
    float4 o=make_float4(acc[i2][0],acc[i2][1],acc[i2][2],acc[i2][3]);
    *(float4*)(C+(size_t)(bm+ty*4+i2)*Nc+bn+tx*4)=o;
  }
}

// fused decode GEMM: C = Xup[labs]@B[0:256] + Xsk@B[256:512]
__global__ __launch_bounds__(256) void k_gemm2(const float* __restrict__ Xup, const int* __restrict__ labs,
    const float* __restrict__ Xsk, const float* __restrict__ B, float* __restrict__ C){
  __shared__ float As[16][68];
  __shared__ float Bs[16][68];
  int tid=threadIdx.x;
  int tx=tid&15, ty=tid>>4;
  int bm=blockIdx.y*64, bn=blockIdx.x*64;
  int lm=tid>>2, lk=(tid&3)*4;
  int kr=tid>>4, nf=(tid&15)*4;
  int arow=labs[bm+lm];
  float acc[4][4]={};
  for(int half=0;half<2;half++){
    const float* A=(half==0)?Xup:Xsk;
    const float* Bh=B+(size_t)half*256*FF;
    int r=(half==0)?arow:(bm+lm);
    for(int k0=0;k0<256;k0+=16){
      float4 a4=*(const float4*)(A+(size_t)r*FF+k0+lk);
      As[lk+0][lm]=a4.x; As[lk+1][lm]=a4.y; As[lk+2][lm]=a4.z; As[lk+3][lm]=a4.w;
      float4 b4=*(const float4*)(Bh+(size_t)(k0+kr)*FF+bn+nf);
      *(float4*)&Bs[kr][nf]=b4;
      __syncthreads();
#pragma unroll
      for(int kk=0;kk<16;kk++){
        float4 av=*(const float4*)&As[kk][ty*4];
        float4 bv=*(const float4*)&Bs[kk][tx*4];
        float am[4]={av.x,av.y,av.z,av.w};
        float bb[4]={bv.x,bv.y,bv.z,bv.w};
#pragma unroll
        for(int i2=0;i2<4;i2++)
#pragma unroll
          for(int j2=0;j2<4;j2++) acc[i2][j2]+=am[i2]*bb[j2];
      }
      __syncthreads();
    }
  }
  for(int i2=0;i2<4;i2++){
    float4 o=make_float4(acc[i2][0],acc[i2][1],acc[i2][2],acc[i2][3]);
    *(float4*)(C+(size_t)(bm+ty*4+i2)*FF+bn+tx*4)=o;
  }
}

__global__ __launch_bounds__(256) void k_gemm16(const float* __restrict__ X, const float* __restrict__ W, float* __restrict__ T){
  int idx=blockIdx.x*256+threadIdx.x;
  if(idx>=NN*16) return;
  int i=idx>>4, o=idx&15;
  float s=0.f;
  for(int kk=0;kk<FF;kk++) s+=X[(size_t)i*FF+kk]*W[kk*16+o];
  T[idx]=s;
}

// ---------------- SpMM (wave per row) + optional fused edge-score ----------------
// if s1!=nullptr: after writing the normalized row, compute h = fb + row@fw (64 outputs),
// p1=h*av[l], p2=h*av[64+l], reduce, write s1/s2 — identical math/order to the old k_edge.
__global__ __launch_bounds__(256) void k_spmm_gcn(const int* __restrict__ rp, const int* __restrict__ cols, const float* __restrict__ vals,
    const float* __restrict__ X, const float* __restrict__ bias, const float* __restrict__ resid, float* __restrict__ out, int act,
    const float* __restrict__ fw, const float* __restrict__ fb, const float* __restrict__ av,
    float* __restrict__ s1, float* __restrict__ s2){
  __shared__ float xr[4][FF];
  int wv=threadIdx.x>>6;
  int wid=blockIdx.x*4+wv;
  int lane=threadIdx.x&63;
  if(wid>=NN) return;
  int e0=rp[wid], e1=rp[wid+1];
  float4 acc=make_float4(0,0,0,0);
  for(int e=e0;e<e1;e++){
    float v=vals[e]; int c=cols[e];
    float4 xv=*(const float4*)(X+(size_t)c*FF+lane*4);
    acc.x+=v*xv.x; acc.y+=v*xv.y; acc.z+=v*xv.z; acc.w+=v*xv.w;
  }
  float4 bv=*(const float4*)(bias+lane*4);
  acc.x+=bv.x; acc.y+=bv.y; acc.z+=bv.z; acc.w+=bv.w;
  if(act==0){
    acc.x=fmaxf(acc.x,0.f); acc.y=fmaxf(acc.y,0.f); acc.z=fmaxf(acc.z,0.f); acc.w=fmaxf(acc.w,0.f);
  } else {
    acc.x=acc.x>0.f?acc.x:expm1f(acc.x); acc.y=acc.y>0.f?acc.y:expm1f(acc.y);
    acc.z=acc.z>0.f?acc.z:expm1f(acc.z); acc.w=acc.w>0.f?acc.w:expm1f(acc.w);
  }
  if(resid){
    float4 r=*(const float4*)(resid+(size_t)wid*FF+lane*4);
    acc.x+=r.x; acc.y+=r.y; acc.z+=r.z; acc.w+=r.w;
  }
  float ss=acc.x*acc.x+acc.y*acc.y+acc.z*acc.z+acc.w*acc.w;
  for(int o=32;o;o>>=1) ss+=__shfl_xor(ss,o);
  float nrm=fmaxf(sqrtf(ss),1e-12f);
  float4 o4=make_float4(acc.x/nrm,acc.y/nrm,acc.z/nrm,acc.w/nrm);
  *(float4*)(out+(size_t)wid*FF+lane*4)=o4;
  if(s1){
    *(float4*)&xr[wv][lane*4]=o4;              // wave-private LDS stash; no cross-wave sharing
    float h=fb[lane];
    const float* xw=&xr[wv][0];
    for(int kk=0;kk<FF;kk++) h+=xw[kk]*fw[kk*64+lane];
    float p1=h*av[lane], p2=h*av[64+lane];
    for(int o=32;o;o>>=1){ p1+=__shfl_xor(p1,o); p2+=__shfl_xor(p2,o); }
    if(lane==0){ s1[wid]=p1; s2[wid]=p2; }
  }
}

// plain SpMM over packed post-cut edges: col = epack & 4095
__global__ __launch_bounds__(256) void k_spmm_plain(const int* __restrict__ rp, const unsigned* __restrict__ epack, const float* __restrict__ vals,
    const float* __restrict__ X, float* __restrict__ out){
  int wid=blockIdx.x*4+(threadIdx.x>>6);
  int lane=threadIdx.x&63;
  if(wid>=NN) return;
  int e0=rp[wid], e1=rp[wid+1];
  float4 acc=make_float4(0,0,0,0);
  for(int e=e0;e<e1;e++){
    if(e>=CAPE) break;
    float v=vals[e]; int c=(int)(epack[e]&4095u);
    float4 xv=*(const float4*)(X+(size_t)c*FF+lane*4);
    acc.x+=v*xv.x; acc.y+=v*xv.y; acc.z+=v*xv.z; acc.w+=v*xv.w;
  }
  *(float4*)(out+(size_t)wid*FF+lane*4)=acc;
}

// att row built in LDS, streamed to dense attB + cand compaction
__global__ __launch_bounds__(256) void k_att_row(const int* __restrict__ rp, const int* __restrict__ cols,
    const float* __restrict__ s1, const float* __restrict__ s2, float* __restrict__ attD, float* __restrict__ cand, Scal* sc){
  __shared__ float row[NN];
  __shared__ int wred[4];
  int i=blockIdx.x, t=threadIdx.x;
  for(int j=t;j<NN;j+=256) row[j]=0.f;
  __syncthreads();
  int e0=rp[i], e1=rp[i+1];
  float s1i=s1[i], s2i=s2[i];
  int nz=0;
  for(int e=e0+t;e<e1;e+=256){
    int j=cols[e];
    float v=(j==i)?1.0f:0.5f*(sigm(s1i+s2[j])+sigm(s1[j]+s2i));
    row[j]=v;
    if(e<CAPE) cand[e]=v;
    if(!(v>0.f)) nz++;
  }
  for(int o=32;o;o>>=1) nz+=__shfl_xor(nz,o);
  if((t&63)==0) wred[t>>6]=nz;
  __syncthreads();
  if(t==0){ int s=wred[0]+wred[1]+wred[2]+wred[3]; if(s) atomicAdd(&sc->nzero,s); }
  float* orow=attD+(size_t)i*NN;
  for(int j=t*4;j<NN;j+=1024) *(float4*)(orow+j)=*(const float4*)&row[j];
}

// ---------------- percentile: hist14 -> pick14 -> collect bucket -> exact select ----------------
__global__ __launch_bounds__(256) void k_hist14(const float* __restrict__ cand, const Scal* __restrict__ sc, unsigned* __restrict__ bins){
  __shared__ unsigned h[16384];
  int t=threadIdx.x;
  for(int b=t;b<16384;b+=256) h[b]=0;
  __syncthreads();
  int n=sc->nnzS; if(n>CAPE) n=CAPE;
  int stride=gridDim.x*256;
  for(int e=blockIdx.x*256+t; e<n; e+=stride){
    float v=cand[e];
    if(v>0.f) atomicAdd(&h[__float_as_uint(v)>>16],1u);
  }
  __syncthreads();
  for(int b=t;b<16384;b+=256){ unsigned c=h[b]; if(c) atomicAdd(&bins[b],c); }
}

__global__ __launch_bounds__(256) void k_pick14(unsigned* __restrict__ bins, Scal* sc){
  __shared__ int part[256];
  __shared__ int selbin; __shared__ int below_sel; __shared__ int sh_r;
  int t=threadIdx.x;
  if(t==0){
    int np=sc->nnzS - sc->nzero;
    float idx=(float)(np-1)*(30.0f/100.0f);
    float fl=floorf(idx), ce=ceilf(idx);
    sc->lo=(int)fl; sc->hi=(int)ce; sc->frac=idx-fl;
    sc->ccount=0; sc->minabove=0xFFFFFFFFu;
    sh_r=(int)fl;
  }
  __syncthreads();
  int r=sh_r;
  int b0=t*64;
  int sum=0;
  for(int u=0;u<64;u++) sum+=(int)bins[b0+u];
  part[t]=sum; __syncthreads();
  for(int o=1;o<256;o<<=1){ int v=(t>=o)?part[t-o]:0; __syncthreads(); part[t]+=v; __syncthreads(); }
  int incl=part[t], excl=incl-sum;
  if(r>=excl && r<incl){
    int run=excl;
    for(int u=0;u<64;u++){
      int c=(int)bins[b0+u];
      if(r<run+c){ selbin=b0+u; below_sel=run; break; }
      run+=c;
    }
  }
  __syncthreads();
  if(t==0){
    sc->rank_rem=r-below_sel;
    sc->below_acc=below_sel;
    sc->prefix=(unsigned)selbin;
  }
  for(int b=t;b<16384;b+=256) bins[b]=0;
}

// collect bucket values: two-pass, block-aggregated
__global__ __launch_bounds__(256) void k_collect(const float* __restrict__ cand, Scal* sc, unsigned* __restrict__ collbuf){
  __shared__ int blkCnt; __shared__ unsigned blkMin; __shared__ int blkBase; __shared__ int wrOff;
  int n=sc->nnzS; if(n>CAPE) n=CAPE;
  unsigned pref=sc->prefix;
  int t=threadIdx.x, lane=t&63;
  if(t==0){ blkCnt=0; blkMin=0xFFFFFFFFu; wrOff=0; }
  __syncthreads();
  int stride=gridDim.x*256;
  int cnt=0; unsigned mn=0xFFFFFFFFu;
  for(int base=blockIdx.x*256; base<n; base+=stride){
    int e=base+t;
    if(e<n){
      float v=cand[e];
      if(v>0.f){
        unsigned bb=__float_as_uint(v);
        unsigned key=bb>>16;
        if(key==pref) cnt++;
        else if(key>pref && bb<mn) mn=bb;
      }
    }
  }
  for(int o=32;o;o>>=1){ cnt+=__shfl_xor(cnt,o); unsigned om=__shfl_xor(mn,o); if(om<mn) mn=om; }
  if(lane==0){ if(cnt) atomicAdd(&blkCnt,cnt); if(mn!=0xFFFFFFFFu) atomicMin(&blkMin,mn); }
  __syncthreads();
  if(t==0){
    blkBase=blkCnt?atomicAdd(&sc->ccount,blkCnt):0;
    if(blkMin!=0xFFFFFFFFu) atomicMin(&sc->minabove,blkMin);
  }
  __syncthreads();
  if(blkCnt==0) return;
  for(int base=blockIdx.x*256; base<n; base+=stride){
    int e=base+t;
    bool inb=false; unsigned bb=0;
    if(e<n){
      float v=cand[e];
      if(v>0.f){ bb=__float_as_uint(v); inb=((bb>>16)==pref); }
    }
    unsigned long long bal=__ballot(inb);
    if(bal){
      int leader=__ffsll(bal)-1;
      int c2=__popcll(bal);
      int wb=0;
      if(lane==leader) wb=atomicAdd(&wrOff,c2);
      wb=__shfl(wb,leader);
      if(inb){
        int rk=__popcll(bal&((1ull<<lane)-1ull));
        int pos=blkBase+wb+rk;
        if(pos<CAPE) collbuf[pos]=bb;
      }
    }
  }
}

// exact select within bucket (8+8 bit LDS hist), in-bucket min-above, cut
__global__ __launch_bounds__(1024) void k_sel2(const unsigned* __restrict__ collbuf, Scal* sc){
  __shared__ unsigned h[256];
  __shared__ int sel1, below1, sel2, below2, cnt2;
  __shared__ unsigned red[1024];
  int t=threadIdx.x;
  int n=sc->ccount; if(n>CAPE) n=CAPE;
  int r=sc->rank_rem;
  if(t<256) h[t]=0;
  __syncthreads();
  for(int e=t;e<n;e+=1024) atomicAdd(&h[(collbuf[e]>>8)&0xFFu],1u);
  __syncthreads();
  if(t==0){
    int run=0;
    for(int b=0;b<256;b++){ int c=(int)h[b]; if(r<run+c){ sel1=b; below1=run; break; } run+=c; }
  }
  __syncthreads();
  int s1b=sel1;
  int r2=r-below1;
  __syncthreads();
  if(t<256) h[t]=0;
  __syncthreads();
  for(int e=t;e<n;e+=1024){ unsigned bb=collbuf[e]; if(((bb>>8)&0xFFu)==(unsigned)s1b) atomicAdd(&h[bb&0xFFu],1u); }
  __syncthreads();
  if(t==0){
    int run=0;
    for(int b=0;b<256;b++){ int c=(int)h[b]; if(r2<run+c){ sel2=b; below2=run; cnt2=c; break; } run+=c; }
  }
  __syncthreads();
  unsigned vlo=(sc->prefix<<16)|((unsigned)s1b<<8)|(unsigned)sel2;
  unsigned mn=0xFFFFFFFFu;
  for(int e=t;e<n;e+=1024){ unsigned bb=collbuf[e]; if(bb>vlo&&bb<mn) mn=bb; }
  red[t]=mn; __syncthreads();
  for(int o=512;o;o>>=1){ if(t<o){ unsigned ob=red[t+o]; if(ob<red[t]) red[t]=ob; } __syncthreads(); }
  if(t==0){
    unsigned minab=red[0]<sc->minabove?red[0]:sc->minabove;
    int c_le=sc->below_acc+below1+below2+cnt2;
    float slo=__uint_as_float(vlo);
    float shi;
    if(sc->hi==sc->lo) shi=slo;
    else if(c_le>sc->hi) shi=slo;
    else shi=__uint_as_float(minab);
    sc->cut=slo*(1.0f-sc->frac)+shi*sc->frac;
  }
}

// ---------------- post-cut CSR (scan-based, packed edges) ----------------
__global__ __launch_bounds__(256) void k_pc_count(const int* __restrict__ rp, const float* __restrict__ cand, const Scal* __restrict__ sc,
    int* __restrict__ rowcnt, float* __restrict__ cntf){
  int wid=blockIdx.x*4+(threadIdx.x>>6);
  int lane=threadIdx.x&63;
  if(wid>=NN) return;
  int e0=rp[wid], e1=rp[wid+1];
  float cut=sc->cut;
  int c=0;
  for(int e=e0+lane;e<e1;e+=64){ if(e<CAPE && cand[e]>=cut) c++; }
  for(int o=32;o;o>>=1) c+=__shfl_xor(c,o);
  if(lane==0){ rowcnt[wid]=c; cntf[wid]=(float)c; }
}

__global__ __launch_bounds__(256) void k_pc_fill(const int* __restrict__ rp, const int* __restrict__ cols, const float* __restrict__ cand,
    const Scal* __restrict__ sc, const int* __restrict__ rp2, unsigned* __restrict__ epack, float* __restrict__ pval,
    const float* __restrict__ cntf){
  int wid=blockIdx.x*4+(threadIdx.x>>6);
  int lane=threadIdx.x&63;
  if(wid>=NN) return;
  int e0=rp[wid], e1=rp[wid+1];
  float cut=sc->cut, cf=cntf[wid];
  int base=rp2[wid];
  for(int eb=e0;eb<e1;eb+=64){
    int e=eb+lane;
    bool p=(e<e1)&&(e<CAPE)&&(cand[e]>=cut);
    unsigned long long m=__ballot(p);
    if(p){
      int pos=base+__popcll(m&((1ull<<lane)-1ull));
      if(pos<CAPE){ epack[pos]=((unsigned)wid<<12)|(unsigned)cols[e]; pval[pos]=cand[e]/cf; }
    }
    base+=__popcll(m);
  }
}

// ---------------- CC + member lists + chunk table: single block, all in LDS ----------------
__global__ __launch_bounds__(1024) void k_cc(const unsigned* __restrict__ epack, Scal* sc,
    int* __restrict__ labk, int* __restrict__ moff_g, int* __restrict__ memb,
    int* __restrict__ choff_g, int* __restrict__ chm0_g, int* __restrict__ chm1_g){
  __shared__ int lab[NN];
  __shared__ int cnt[NN];
  __shared__ int mof[NN];
  __shared__ int s[1024];
  __shared__ int chg, chg2;
  int t=threadIdx.x;
  for(int i=t;i<NN;i+=1024){ lab[i]=i; cnt[i]=0; }
  int n2=sc->nnz2; if(n2>CAPE) n2=CAPE;
  __syncthreads();
  for(int it=0;it<16;it++){
    if(t==0) chg=0;
    __syncthreads();
    for(int e=t;e<n2;e+=1024){
      unsigned p=epack[e];
      int i=(int)(p>>12), j=(int)(p&4095u);
      if(i<j){
        int li=lab[i], lj=lab[j];
        if(lj<li){ if(atomicMin(&lab[i],lj)>lj) chg=1; }
        else if(li<lj){ if(atomicMin(&lab[j],li)>li) chg=1; }
      }
    }
    __syncthreads();
    for(;;){
      if(t==0) chg2=0;
      __syncthreads();
      int l0=lab[t], l1=lab[t+1024], l2=lab[t+2048];
      int v0=lab[l0], v1=lab[l1], v2=lab[l2];
      __syncthreads();
      if(v0<l0){ lab[t]=v0; chg2=1; }
      if(v1<l1){ lab[t+1024]=v1; chg2=1; }
      if(v2<l2){ lab[t+2048]=v2; chg2=1; }
      __syncthreads();
      if(!chg2) break;
      if(t==0) chg=1;
      __syncthreads();
    }
    if(!chg) break;
    __syncthreads();
  }
  for(int i=t;i<NN;i+=1024){ int l=lab[i]; labk[i]=l; atomicAdd(&cnt[l],1); }
  __syncthreads();
  int a0=cnt[t*3+0], a1=cnt[t*3+1], a2=cnt[t*3+2];
  int loc=a0+a1+a2;
  s[t]=loc; __syncthreads();
  for(int o=1;o<1024;o<<=1){ int v=(t>=o)?s[t-o]:0; __syncthreads(); s[t]+=v; __syncthreads(); }
  int excl=s[t]-loc;
  __syncthreads();
  mof[t*3+0]=excl; mof[t*3+1]=excl+a0; mof[t*3+2]=excl+a0+a1;
  cnt[t*3+0]=excl; cnt[t*3+1]=excl+a0; cnt[t*3+2]=excl+a0+a1;
  moff_g[t*3+0]=excl; moff_g[t*3+1]=excl+a0; moff_g[t*3+2]=excl+a0+a1;
  if(t==1023) moff_g[NN]=s[t];
  __syncthreads();
  int ch0=(a0+63)>>6, ch1=(a1+63)>>6, ch2=(a2+63)>>6;
  int locc=ch0+ch1+ch2;
  s[t]=locc; __syncthreads();
  for(int o=1;o<1024;o<<=1){ int v=(t>=o)?s[t-o]:0; __syncthreads(); s[t]+=v; __syncthreads(); }
  int cexcl=s[t]-locc;
  choff_g[t*3+0]=cexcl; choff_g[t*3+1]=cexcl+ch0; choff_g[t*3+2]=cexcl+ch0+ch1;
  if(t==1023){ choff_g[NN]=s[t]; sc->ncht=s[t]; }
  {
    int bases[3]={cexcl,cexcl+ch0,cexcl+ch0+ch1};
    int cnts[3]={a0,a1,a2};
    int nqs[3]={ch0,ch1,ch2};
    for(int u=0;u<3;u++){
      int m0=mof[t*3+u];
      int me=m0+cnts[u];
      for(int q=0;q<nqs[u];q++){
        int idx=bases[u]+q;
        if(idx<MAXCH){
          chm0_g[idx]=m0+q*64;
          int e2=m0+q*64+64; chm1_g[idx]=e2<me?e2:me;
        }
      }
    }
  }
  __syncthreads();
  int lane=t&63, wv=t>>6;
  for(int b=0;b<3;b++){
    int j=b*1024+t;
    int myl=lab[j];
    int rank_w=0,total=0;
#pragma unroll
    for(int l=0;l<64;l++){
      int lb=__shfl(myl,l);
      if(lb==myl){ total++; if(l<lane) rank_w++; }
    }
    for(int w=0;w<16;w++){
      if(wv==w){
        int base=cnt[myl];
        memb[base+rank_w]=j;
        if(rank_w==0) cnt[myl]=base+total;
      }
      __syncthreads();
    }
  }
}

// ---------------- a2 = C adj C^T: per-block LDS hash (integer-exact), flush to global ----------------
__global__ __launch_bounds__(256) void k_a2e(const int* __restrict__ rowsA, const int* __restrict__ colsA_, const float* __restrict__ aval,
    const Scal* __restrict__ sc, const int* __restrict__ labk, float* __restrict__ dense){
  __shared__ int hkey[HSZ];
  __shared__ unsigned hv[HSZ];
  int t=threadIdx.x;
  for(int i=t;i<HSZ;i+=256){ hkey[i]=-1; hv[i]=0; }
  __syncthreads();
  int n=sc->nnzS; if(n>CAPE) n=CAPE;
  int stride=gridDim.x*256;
  for(int e=blockIdx.x*256+t; e<n; e+=stride){
    float a=aval[e];
    if(a!=0.f){
      int key=labk[rowsA[e]]*NN+labk[colsA_[e]];
      unsigned val=(unsigned)a;
      unsigned hsh=((unsigned)key*2654435761u)&(HSZ-1);
      for(;;){
        int k0=atomicCAS(&hkey[hsh],-1,key);
        if(k0==-1||k0==key){ atomicAdd(&hv[hsh],val); break; }
        hsh=(hsh+1)&(HSZ-1);
      }
    }
  }
  __syncthreads();
  for(int i=t;i<HSZ;i+=256){
    int k0=hkey[i];
    if(k0>=0) atomicAdd(&dense[(size_t)k0],(float)hv[i]);
  }
}

// ---------------- x2: chunked deterministic segmented reduction ----------------
__global__ __launch_bounds__(256) void k_x2p(const float* __restrict__ y, const int* __restrict__ memb,
    const int* __restrict__ chm0, const int* __restrict__ chm1, const Scal* __restrict__ sc, float* __restrict__ partial){
  int b=blockIdx.x;
  if(b>=sc->ncht||b>=MAXCH) return;
  int t=threadIdx.x;
  int m0=chm0[b], m1=chm1[b];
  float acc=0.f;
#pragma unroll 4
  for(int m=m0;m<m1;m++) acc+=y[(size_t)memb[m]*FF+t];
  partial[(size_t)b*FF+t]=acc;
}
__global__ __launch_bounds__(256) void k_x2f(const int* __restrict__ choff, const float* __restrict__ partial, float* __restrict__ out){
  int c=blockIdx.x, t=threadIdx.x;
  int q0=choff[c], q1=choff[c+1];
  float acc=0.f;
  for(int q=q0;q<q1&&q<MAXCH;q++) acc+=partial[(size_t)q*FF+t];
  __shared__ float red[256];
  red[t]=acc*acc; __syncthreads();
  for(int o=128;o;o>>=1){ if(t<o) red[t]+=red[t+o]; __syncthreads(); }
  float nrm=fmaxf(sqrtf(red[0]),1e-12f);
  out[(size_t)c*FF+t]=(q1>q0)?acc/nrm:0.f;
}

__global__ __launch_bounds__(256) void k_final(const int* __restrict__ rp, const int* __restrict__ cols, const float* __restrict__ vals,
    const float* __restrict__ T, const float* __restrict__ bias, float* __restrict__ logp){
  int i=blockIdx.x*256+threadIdx.x;
  if(i>=NN) return;
  float o[16];
#pragma unroll
  for(int f=0;f<16;f++) o[f]=bias[f];
  int e1=rp[i+1];
  for(int e=rp[i];e<e1;e++){
    float v=vals[e]; const float* tr=T+(size_t)cols[e]*16;
#pragma unroll
    for(int f=0;f<16;f++) o[f]+=v*tr[f];
  }
  float m=o[0];
#pragma unroll
  for(int f=1;f<16;f++) m=fmaxf(m,o[f]);
  float ssum=0.f;
#pragma unroll
  for(int f=0;f<16;f++) ssum+=expf(o[f]-m);
  float lse=logf(ssum);
#pragma unroll
  for(int f=0;f<16;f++) logp[(size_t)i*16+f]=o[f]-m-lse;
}

// full-write Cs: CsB[l][c][j] = (labsv[l*NN+j]==c), no memset needed
__global__ __launch_bounds__(256) void k_cs_full(const int* __restrict__ labsv, float* __restrict__ CsB){
  int idx=blockIdx.x*256+threadIdx.x;
  const int ROW4=NN/4;
  int l=idx/(NN*ROW4);
  int rem=idx-l*(NN*ROW4);
  int c=rem/ROW4;
  int j4=(rem-c*ROW4)*4;
  const int* lb=labsv+(size_t)l*NN+j4;
  int4 lv=*(const int4*)lb;
  float4 o;
  o.x=(lv.x==c)?1.0f:0.0f;
  o.y=(lv.y==c)?1.0f:0.0f;
  o.z=(lv.z==c)?1.0f:0.0f;
  o.w=(lv.w==c)?1.0f:0.0f;
  *(float4*)(CsB+(size_t)idx*4)=o;
}

// ================= host =================
extern "C" void kernel_launch(void* const* d_in, const int* in_sizes, int n_in,
                              void* d_out, int out_size, void* d_ws, size_t ws_size,
                              hipStream_t stream) {
  (void)in_sizes; (void)n_in; (void)out_size;
  const float* x_in =(const float*)d_in[0];
  const float* adjC =(const float*)d_in[1];
  const float* adj  =(const float*)d_in[2];
  const float* encW0=(const float*)d_in[3];
  const float* encb0=(const float*)d_in[4];
  const float* encW =(const float*)d_in[5];
  const float* encb =(const float*)d_in[6];
  const float* fcW  =(const float*)d_in[7];
  const float* fcb  =(const float*)d_in[8];
  const float* aW   =(const float*)d_in[9];
  const float* decW =(const float*)d_in[10];
  const float* decb =(const float*)d_in[11];
  const float* decWo=(const float*)d_in[12];
  const float* decbo=(const float*)d_in[13];
  float* out=(float*)d_out;

  float* logp=out;
  float* CsB = out + (size_t)NN*16;
  float* attB= CsB + 3ull*NN*NN;
  float* slot1 = CsB + (size_t)NN*NN;
  float* xs[4]; for(int i=0;i<4;i++) xs[i]=slot1+(size_t)i*NN*FF;
  float* xcur=slot1+(size_t)4*NN*FF;
  float* ybuf=slot1+(size_t)5*NN*FF;
  float* tbuf=slot1+(size_t)6*NN*FF;

  char* w=(char*)d_ws; size_t off=0;
  auto alc=[&](size_t b)->void*{ off=(off+255)&~(size_t)255; void* r=w+off; off+=b; return r; };
  Scal* sc=(Scal*)alc(sizeof(Scal));
  int* rowcnt=(int*)alc((size_t)NN*4);
  int* rp[4]; for(int i=0;i<4;i++) rp[i]=(int*)alc((size_t)(NN+1)*4);
  int* rp2=(int*)alc((size_t)(NN+1)*4);
  int* colsA[4]; float* acv[4];
  for(int i=0;i<4;i++){ colsA[i]=(int*)alc((size_t)CAPE*4); acv[i]=(float*)alc((size_t)CAPE*4); }
  float* avalS=(float*)alc((size_t)CAPE*4);
  int* rowsA=(int*)alc((size_t)CAPE*4);
  float* cand=(float*)alc((size_t)CAPE*4);
  unsigned* collbuf=(unsigned*)alc((size_t)CAPE*4);
  unsigned* epack=(unsigned*)alc((size_t)CAPE*4);
  float* pval=(float*)alc((size_t)CAPE*4);
  unsigned* bins=(unsigned*)alc((size_t)16384*4);
  int* labsv=(int*)alc((size_t)3*NN*4);
  int* moff=(int*)alc((size_t)(NN+1)*4);
  int* memb=(int*)alc((size_t)NN*4);
  int* choff=(int*)alc((size_t)(NN+1)*4);
  int* chm0=(int*)alc((size_t)MAXCH*4);
  int* chm1=(int*)alc((size_t)MAXCH*4);
  float* partial=(float*)alc((size_t)MAXCH*FF*4);
  float* cntf=(float*)alc((size_t)NN*4);
  float* s1=(float*)alc((size_t)NN*4);
  float* s2v=(float*)alc((size_t)NN*4);
  float* Dv=(float*)alc((size_t)NN*4);
  float* t16=(float*)alc((size_t)NN*16*4);
  float* dense;
  size_t denseB=(size_t)NN*NN*4;
  if(ws_size>=off+denseB+4096) dense=(float*)alc(denseB);
  else dense=CsB;

  auto build_csr=[&](const float* Ad, const float* ACd, const float* Dp, int lvl){
    k_count_dense<<<NN,256,0,stream>>>(Ad,rowcnt,Dv);
    k_scan<<<1,1024,0,stream>>>(rowcnt,rp[lvl],&sc->nnzS,sc);
    k_fill_dense<<<NN,256,0,stream>>>(Ad,ACd,Dp,rp[lvl],rowsA,colsA[lvl],avalS,acv[lvl]);
  };

  k_init<<<64,256,0,stream>>>(bins);
  build_csr(adj,adjC,nullptr,0);

  // ---------- encode ----------
  for(int k=0;k<3;k++){
    const float* xin=(k==0)?x_in:xcur;
    const float* Wk=(k==0)?encW0:(encW+(size_t)(k-1)*FF*FF);
    const float* bk=(k==0)?encb0:(encb+(size_t)(k-1)*FF);
    int K=(k==0)?512:FF;
    k_gemm<<<dim3(FF/64,NN/64),256,0,stream>>>(xin,Wk,tbuf,NN,K,FF);
    // fused spmm + edge-score (s1/s2 computed from the normalized output row)
    k_spmm_gcn<<<NN/4,256,0,stream>>>(rp[k],colsA[k],acv[k],tbuf,bk,(k==0)?nullptr:xcur,xs[k],0,
                                      fcW+(size_t)k*FF*64,fcb+(size_t)k*64,aW+(size_t)k*128,s1,s2v);

    k_att_row<<<NN,256,0,stream>>>(rp[k],colsA[k],s1,s2v,attB+(size_t)k*NN*NN,cand,sc);

    // percentile: hist14 -> pick14 -> collect (block-aggregated) -> exact select
    k_hist14<<<64,256,0,stream>>>(cand,sc,bins);
    k_pick14<<<1,256,0,stream>>>(bins,sc);
    k_collect<<<64,256,0,stream>>>(cand,sc,collbuf);
    k_sel2<<<1,1024,0,stream>>>(collbuf,sc);

    // post-cut CSR (scan-based, packed edges)
    k_pc_count<<<NN/4,256,0,stream>>>(rp[k],cand,sc,rowcnt,cntf);
    k_scan<<<1,1024,0,stream>>>(rowcnt,rp2,&sc->nnz2,sc);
    k_pc_fill<<<NN/4,256,0,stream>>>(rp[k],colsA[k],cand,sc,rp2,epack,pval,cntf);

    // CC + member lists + chunk table (one block, packed edges + full shortcut)
    k_cc<<<1,1024,0,stream>>>(epack,sc,labsv+(size_t)k*NN,moff,memb,choff,chm0,chm1);

    // a2 (per-block LDS hash, integer-exact); dense zeroed: memset at level 0, sparse wipe after
    if(k==0) hipMemsetAsync(dense,0,denseB,stream);
    k_a2e<<<256,256,0,stream>>>(rowsA,colsA[k],avalS,sc,labsv+(size_t)k*NN,dense);

    // x2
    k_spmm_plain<<<NN/4,256,0,stream>>>(rp2,epack,pval,xs[k],ybuf);
    k_x2p<<<MAXCH,256,0,stream>>>(ybuf,memb,chm0,chm1,sc,partial);
    k_x2f<<<NN,256,0,stream>>>(choff,partial,xcur);

    build_csr(dense,nullptr,Dv,k+1);
    if(k<2) k_wipe<<<CAPE/256,256,0,stream>>>(rowsA,colsA[k+1],sc,dense);
  }

  // ---------- bottleneck ----------
  k_gemm<<<dim3(FF/64,NN/64),256,0,stream>>>(xcur,encW+(size_t)2*FF*FF,tbuf,NN,FF,FF);
  k_spmm_gcn<<<NN/4,256,0,stream>>>(rp[3],colsA[3],acv[3],tbuf,encb+(size_t)2*FF,nullptr,xs[3],1,
                                    nullptr,nullptr,nullptr,nullptr,nullptr);

  // ---------- decode (fused unpool+concat GEMM) ----------
  float* xd=xs[3];
  float* outsb[3]={xcur,ybuf,xcur};
  for(int k=0;k<3;k++){
    int lev=2-k;
    k_gemm2<<<dim3(FF/64,NN/64),256,0,stream>>>(xd,labsv+(size_t)lev*NN,xs[lev],decW+(size_t)k*512*FF,tbuf);
    k_spmm_gcn<<<NN/4,256,0,stream>>>(rp[lev],colsA[lev],acv[lev],tbuf,decb+(size_t)k*FF,nullptr,outsb[k],1,
                                      nullptr,nullptr,nullptr,nullptr,nullptr);
    xd=outsb[k];
  }

  // ---------- final gcn + log_softmax ----------
  k_gemm16<<<(NN*16)/256,256,0,stream>>>(xd,decWo,t16);
  k_final<<<(NN+255)/256,256,0,stream>>>(rp[0],colsA[0],acv[0],t16,decbo,logp);

  // ---------- materialize Cs (full write, no memset) ----------
  k_cs_full<<<(3*NN*(NN/4))/256,256,0,stream>>>(labsv,CsB);
}

// Round 18
// 835.107 us; speedup vs baseline: 1.0251x; 1.0251x over previous
//
#include <hip/hip_runtime.h>
#include <math.h>

#define NN 3072
#define FF 256
#define CAPE (1<<18)
#define MAXCH 3200
#define HSZ 2048

struct Scal {
  int nnzS, nnz2, nzero, ncht, ccount;
  int lo, hi, rank_rem, below_acc;
  unsigned prefix, minabove;
  float frac, cut;
};

__device__ __forceinline__ float sigm(float x){ return 1.0f/(1.0f+expf(-x)); }

// ---------------- init: zero bins (once) ----------------
__global__ __launch_bounds__(256) void k_init(unsigned* __restrict__ bins){
  int i=blockIdx.x*256+threadIdx.x;
  if(i<16384) bins[i]=0;
}

// ---------------- CSR build ----------------
__global__ __launch_bounds__(256) void k_count_dense(const float* __restrict__ A, int* __restrict__ rowcnt, float* __restrict__ Drow){
  int i=blockIdx.x, t=threadIdx.x;
  int c=0; float sm=0.f;
  for(int j=t;j<NN;j+=256){ float a=A[(size_t)i*NN+j]; if(a!=0.0f||j==i) c++; sm+=a; }
  __shared__ int s[256]; __shared__ float fs[256];
  s[t]=c; fs[t]=sm; __syncthreads();
  for(int o=128;o;o>>=1){ if(t<o){ s[t]+=s[t+o]; fs[t]+=fs[t+o]; } __syncthreads(); }
  if(t==0){ rowcnt[i]=s[0]; if(Drow) Drow[i]=sqrtf(fs[0]+1.0f); }
}

// scan; also zeroes sc->nzero (consumed later by pick14; re-zero mid-level is harmless)
__global__ __launch_bounds__(1024) void k_scan(const int* __restrict__ cnt, int* __restrict__ rp, int* __restrict__ total, Scal* sc){
  int t=threadIdx.x;
  if(t==0) sc->nzero=0;
  int a0=cnt[t*3+0], a1=cnt[t*3+1], a2=cnt[t*3+2];
  int loc=a0+a1+a2;
  __shared__ int s[1024];
  s[t]=loc; __syncthreads();
  for(int o=1;o<1024;o<<=1){ int v=(t>=o)?s[t-o]:0; __syncthreads(); s[t]+=v; __syncthreads(); }
  int excl=s[t]-loc;
  rp[t*3+0]=excl; rp[t*3+1]=excl+a0; rp[t*3+2]=excl+a0+a1;
  if(t==1023){ rp[NN]=s[t]; *total=s[t]; }
}

// structure = (A!=0) | diag.  acval: from dense ACd (level 0) or (a+I)/(Di*Dj) (levels>=1)
__global__ __launch_bounds__(256) void k_fill_dense(const float* __restrict__ A, const float* __restrict__ ACd, const float* __restrict__ D,
    const int* __restrict__ rp, int* __restrict__ rows, int* __restrict__ cols, float* __restrict__ aval, float* __restrict__ acval){
  int i=blockIdx.x, t=threadIdx.x;
  const int CH=NN/256;
  int j0=t*CH; int c=0;
  for(int u=0;u<CH;u++){ int j=j0+u; float a=A[(size_t)i*NN+j]; if(a!=0.0f||j==i) c++; }
  __shared__ int s[256]; s[t]=c; __syncthreads();
  for(int o=1;o<256;o<<=1){ int v=(t>=o)?s[t-o]:0; __syncthreads(); s[t]+=v; __syncthreads(); }
  int pos=rp[i]+s[t]-c;
  float Di = D?D[i]:0.0f;
  for(int u=0;u<CH;u++){ int j=j0+u; float a=A[(size_t)i*NN+j];
    if(a!=0.0f||j==i){
      if(pos<CAPE){
        rows[pos]=i; cols[pos]=j; aval[pos]=a;
        acval[pos]= ACd? ACd[(size_t)i*NN+j] : (a+(j==i?1.0f:0.0f))/(Di*D[j]);
      }
      pos++;
    }
  }
}

// sparse wipe of dense using the just-built CSR (structure covers all nonzeros)
__global__ __launch_bounds__(256) void k_wipe(const int* __restrict__ rows, const int* __restrict__ cols, const Scal* __restrict__ sc,
    float* __restrict__ dense){
  int e=blockIdx.x*256+threadIdx.x;
  int n=sc->nnzS; if(n>CAPE) n=CAPE;
  if(e<n) dense[(size_t)rows[e]*NN+cols[e]]=0.f;
}

// ---------------- dense GEMM (f32, 64x64 tile, direct store) ----------------
__global__ __launch_bounds__(256) void k_gemm(const float* __restrict__ A, const float* __restrict__ B, float* __restrict__ C,
                                              int M, int K, int Nc){
  __shared__ float As[16][68];
  __shared__ float Bs[16][68];
  int tid=threadIdx.x;
  int tx=tid&15, ty=tid>>4;
  int bm=blockIdx.y*64, bn=blockIdx.x*64;
  int lm=tid>>2, lk=(tid&3)*4;
  int kr=tid>>4, nf=(tid&15)*4;
  float acc[4][4]={};
  for(int k0=0;k0<K;k0+=16){
    float4 a4=*(const float4*)(A+(size_t)(bm+lm)*K+k0+lk);
    As[lk+0][lm]=a4.x; As[lk+1][lm]=a4.y; As[lk+2][lm]=a4.z; As[lk+3][lm]=a4.w;
    float4 b4=*(const float4*)(B+(size_t)(k0+kr)*Nc+bn+nf);
    *(float4*)&Bs[kr][nf]=b4;
    __syncthreads();
#pragma unroll
    for(int kk=0;kk<16;kk++){
      float4 av=*(const float4*)&As[kk][ty*4];
      float4 bv=*(const float4*)&Bs[kk][tx*4];
      float am[4]={av.x,av.y,av.z,av.w};
      float bb[4]={bv.x,bv.y,bv.z,bv.w};
#pragma unroll
      for(int i2=0;i2<4;i2++)
#pragma unroll
        for(int j2=0;j2<4;j2++) acc[i2][j2]+=am[i2]*bb[j2];
    }
    __syncthreads();
  }
  for(int i2=0;i2<4;i2++){
    float4 o=make_float4(acc[i2][0],acc[i2][1],acc[i2][2],acc[i2][3]);
    *(float4*)(C+(size_t)(bm+ty*4+i2)*Nc+bn+tx*4)=o;
  }
}

// fused decode GEMM: C = Xup[labs]@B[0:256] + Xsk@B[256:512]
__global__ __launch_bounds__(256) void k_gemm2(const float* __restrict__ Xup, const int* __restrict__ labs,
    const float* __restrict__ Xsk, const float* __restrict__ B, float* __restrict__ C){
  __shared__ float As[16][68];
  __shared__ float Bs[16][68];
  int tid=threadIdx.x;
  int tx=tid&15, ty=tid>>4;
  int bm=blockIdx.y*64, bn=blockIdx.x*64;
  int lm=tid>>2, lk=(tid&3)*4;
  int kr=tid>>4, nf=(tid&15)*4;
  int arow=labs[bm+lm];
  float acc[4][4]={};
  for(int half=0;half<2;half++){
    const float* A=(half==0)?Xup:Xsk;
    const float* Bh=B+(size_t)half*256*FF;
    int r=(half==0)?arow:(bm+lm);
    for(int k0=0;k0<256;k0+=16){
      float4 a4=*(const float4*)(A+(size_t)r*FF+k0+lk);
      As[lk+0][lm]=a4.x; As[lk+1][lm]=a4.y; As[lk+2][lm]=a4.z; As[lk+3][lm]=a4.w;
      float4 b4=*(const float4*)(Bh+(size_t)(k0+kr)*FF+bn+nf);
      *(float4*)&Bs[kr][nf]=b4;
      __syncthreads();
#pragma unroll
      for(int kk=0;kk<16;kk++){
        float4 av=*(const float4*)&As[kk][ty*4];
        float4 bv=*(const float4*)&Bs[kk][tx*4];
        float am[4]={av.x,av.y,av.z,av.w};
        float bb[4]={bv.x,bv.y,bv.z,bv.w};
#pragma unroll
        for(int i2=0;i2<4;i2++)
#pragma unroll
          for(int j2=0;j2<4;j2++) acc[i2][j2]+=am[i2]*bb[j2];
      }
      __syncthreads();
    }
  }
  for(int i2=0;i2<4;i2++){
    float4 o=make_float4(acc[i2][0],acc[i2][1],acc[i2][2],acc[i2][3]);
    *(float4*)(C+(size_t)(bm+ty*4+i2)*FF+bn+tx*4)=o;
  }
}

__global__ __launch_bounds__(256) void k_gemm16(const float* __restrict__ X, const float* __restrict__ W, float* __restrict__ T){
  int idx=blockIdx.x*256+threadIdx.x;
  if(idx>=NN*16) return;
  int i=idx>>4, o=idx&15;
  float s=0.f;
  for(int kk=0;kk<FF;kk++) s+=X[(size_t)i*FF+kk]*W[kk*16+o];
  T[idx]=s;
}

// ---------------- SpMM (wave per row) + optional fused edge-score ----------------
// if s1!=nullptr: after writing the normalized row, compute h = fb + row@fw (64 outputs),
// p1=h*av[l], p2=h*av[64+l], reduce, write s1/s2 — identical math/order to the old k_edge.
__global__ __launch_bounds__(256) void k_spmm_gcn(const int* __restrict__ rp, const int* __restrict__ cols, const float* __restrict__ vals,
    const float* __restrict__ X, const float* __restrict__ bias, const float* __restrict__ resid, float* __restrict__ out, int act,
    const float* __restrict__ fw, const float* __restrict__ fb, const float* __restrict__ av,
    float* __restrict__ s1, float* __restrict__ s2){
  __shared__ float xr[4][FF];
  int wv=threadIdx.x>>6;
  int wid=blockIdx.x*4+wv;
  int lane=threadIdx.x&63;
  if(wid>=NN) return;
  int e0=rp[wid], e1=rp[wid+1];
  float4 acc=make_float4(0,0,0,0);
  for(int e=e0;e<e1;e++){
    float v=vals[e]; int c=cols[e];
    float4 xv=*(const float4*)(X+(size_t)c*FF+lane*4);
    acc.x+=v*xv.x; acc.y+=v*xv.y; acc.z+=v*xv.z; acc.w+=v*xv.w;
  }
  float4 bv=*(const float4*)(bias+lane*4);
  acc.x+=bv.x; acc.y+=bv.y; acc.z+=bv.z; acc.w+=bv.w;
  if(act==0){
    acc.x=fmaxf(acc.x,0.f); acc.y=fmaxf(acc.y,0.f); acc.z=fmaxf(acc.z,0.f); acc.w=fmaxf(acc.w,0.f);
  } else {
    acc.x=acc.x>0.f?acc.x:expm1f(acc.x); acc.y=acc.y>0.f?acc.y:expm1f(acc.y);
    acc.z=acc.z>0.f?acc.z:expm1f(acc.z); acc.w=acc.w>0.f?acc.w:expm1f(acc.w);
  }
  if(resid){
    float4 r=*(const float4*)(resid+(size_t)wid*FF+lane*4);
    acc.x+=r.x; acc.y+=r.y; acc.z+=r.z; acc.w+=r.w;
  }
  float ss=acc.x*acc.x+acc.y*acc.y+acc.z*acc.z+acc.w*acc.w;
  for(int o=32;o;o>>=1) ss+=__shfl_xor(ss,o);
  float nrm=fmaxf(sqrtf(ss),1e-12f);
  float4 o4=make_float4(acc.x/nrm,acc.y/nrm,acc.z/nrm,acc.w/nrm);
  *(float4*)(out+(size_t)wid*FF+lane*4)=o4;
  if(s1){
    *(float4*)&xr[wv][lane*4]=o4;              // wave-private LDS stash; no cross-wave sharing
    float h=fb[lane];
    const float* xw=&xr[wv][0];
    for(int kk=0;kk<FF;kk++) h+=xw[kk]*fw[kk*64+lane];
    float p1=h*av[lane], p2=h*av[64+lane];
    for(int o=32;o;o>>=1){ p1+=__shfl_xor(p1,o); p2+=__shfl_xor(p2,o); }
    if(lane==0){ s1[wid]=p1; s2[wid]=p2; }
  }
}

// plain SpMM over packed post-cut edges: col = epack & 4095
__global__ __launch_bounds__(256) void k_spmm_plain(const int* __restrict__ rp, const unsigned* __restrict__ epack, const float* __restrict__ vals,
    const float* __restrict__ X, float* __restrict__ out){
  int wid=blockIdx.x*4+(threadIdx.x>>6);
  int lane=threadIdx.x&63;
  if(wid>=NN) return;
  int e0=rp[wid], e1=rp[wid+1];
  float4 acc=make_float4(0,0,0,0);
  for(int e=e0;e<e1;e++){
    if(e>=CAPE) break;
    float v=vals[e]; int c=(int)(epack[e]&4095u);
    float4 xv=*(const float4*)(X+(size_t)c*FF+lane*4);
    acc.x+=v*xv.x; acc.y+=v*xv.y; acc.z+=v*xv.z; acc.w+=v*xv.w;
  }
  *(float4*)(out+(size_t)wid*FF+lane*4)=acc;
}

// att row built in LDS, streamed to dense attB + cand compaction
__global__ __launch_bounds__(256) void k_att_row(const int* __restrict__ rp, const int* __restrict__ cols,
    const float* __restrict__ s1, const float* __restrict__ s2, float* __restrict__ attD, float* __restrict__ cand, Scal* sc){
  __shared__ float row[NN];
  __shared__ int wred[4];
  int i=blockIdx.x, t=threadIdx.x;
  for(int j=t;j<NN;j+=256) row[j]=0.f;
  __syncthreads();
  int e0=rp[i], e1=rp[i+1];
  float s1i=s1[i], s2i=s2[i];
  int nz=0;
  for(int e=e0+t;e<e1;e+=256){
    int j=cols[e];
    float v=(j==i)?1.0f:0.5f*(sigm(s1i+s2[j])+sigm(s1[j]+s2i));
    row[j]=v;
    if(e<CAPE) cand[e]=v;
    if(!(v>0.f)) nz++;
  }
  for(int o=32;o;o>>=1) nz+=__shfl_xor(nz,o);
  if((t&63)==0) wred[t>>6]=nz;
  __syncthreads();
  if(t==0){ int s=wred[0]+wred[1]+wred[2]+wred[3]; if(s) atomicAdd(&sc->nzero,s); }
  float* orow=attD+(size_t)i*NN;
  for(int j=t*4;j<NN;j+=1024) *(float4*)(orow+j)=*(const float4*)&row[j];
}

// ---------------- percentile: hist14 -> pick14 -> collect bucket -> exact select ----------------
__global__ __launch_bounds__(256) void k_hist14(const float* __restrict__ cand, const Scal* __restrict__ sc, unsigned* __restrict__ bins){
  __shared__ unsigned h[16384];
  int t=threadIdx.x;
  for(int b=t;b<16384;b+=256) h[b]=0;
  __syncthreads();
  int n=sc->nnzS; if(n>CAPE) n=CAPE;
  int stride=gridDim.x*256;
  for(int e=blockIdx.x*256+t; e<n; e+=stride){
    float v=cand[e];
    if(v>0.f) atomicAdd(&h[__float_as_uint(v)>>16],1u);
  }
  __syncthreads();
  for(int b=t;b<16384;b+=256){ unsigned c=h[b]; if(c) atomicAdd(&bins[b],c); }
}

__global__ __launch_bounds__(256) void k_pick14(unsigned* __restrict__ bins, Scal* sc){
  __shared__ int part[256];
  __shared__ int selbin; __shared__ int below_sel; __shared__ int sh_r;
  int t=threadIdx.x;
  if(t==0){
    int np=sc->nnzS - sc->nzero;
    float idx=(float)(np-1)*(30.0f/100.0f);
    float fl=floorf(idx), ce=ceilf(idx);
    sc->lo=(int)fl; sc->hi=(int)ce; sc->frac=idx-fl;
    sc->ccount=0; sc->minabove=0xFFFFFFFFu;
    sh_r=(int)fl;
  }
  __syncthreads();
  int r=sh_r;
  int b0=t*64;
  int sum=0;
  for(int u=0;u<64;u++) sum+=(int)bins[b0+u];
  part[t]=sum; __syncthreads();
  for(int o=1;o<256;o<<=1){ int v=(t>=o)?part[t-o]:0; __syncthreads(); part[t]+=v; __syncthreads(); }
  int incl=part[t], excl=incl-sum;
  if(r>=excl && r<incl){
    int run=excl;
    for(int u=0;u<64;u++){
      int c=(int)bins[b0+u];
      if(r<run+c){ selbin=b0+u; below_sel=run; break; }
      run+=c;
    }
  }
  __syncthreads();
  if(t==0){
    sc->rank_rem=r-below_sel;
    sc->below_acc=below_sel;
    sc->prefix=(unsigned)selbin;
  }
  for(int b=t;b<16384;b+=256) bins[b]=0;
}

// collect bucket values: two-pass, block-aggregated
__global__ __launch_bounds__(256) void k_collect(const float* __restrict__ cand, Scal* sc, unsigned* __restrict__ collbuf){
  __shared__ int blkCnt; __shared__ unsigned blkMin; __shared__ int blkBase; __shared__ int wrOff;
  int n=sc->nnzS; if(n>CAPE) n=CAPE;
  unsigned pref=sc->prefix;
  int t=threadIdx.x, lane=t&63;
  if(t==0){ blkCnt=0; blkMin=0xFFFFFFFFu; wrOff=0; }
  __syncthreads();
  int stride=gridDim.x*256;
  int cnt=0; unsigned mn=0xFFFFFFFFu;
  for(int base=blockIdx.x*256; base<n; base+=stride){
    int e=base+t;
    if(e<n){
      float v=cand[e];
      if(v>0.f){
        unsigned bb=__float_as_uint(v);
        unsigned key=bb>>16;
        if(key==pref) cnt++;
        else if(key>pref && bb<mn) mn=bb;
      }
    }
  }
  for(int o=32;o;o>>=1){ cnt+=__shfl_xor(cnt,o); unsigned om=__shfl_xor(mn,o); if(om<mn) mn=om; }
  if(lane==0){ if(cnt) atomicAdd(&blkCnt,cnt); if(mn!=0xFFFFFFFFu) atomicMin(&blkMin,mn); }
  __syncthreads();
  if(t==0){
    blkBase=blkCnt?atomicAdd(&sc->ccount,blkCnt):0;
    if(blkMin!=0xFFFFFFFFu) atomicMin(&sc->minabove,blkMin);
  }
  __syncthreads();
  if(blkCnt==0) return;
  for(int base=blockIdx.x*256; base<n; base+=stride){
    int e=base+t;
    bool inb=false; unsigned bb=0;
    if(e<n){
      float v=cand[e];
      if(v>0.f){ bb=__float_as_uint(v); inb=((bb>>16)==pref); }
    }
    unsigned long long bal=__ballot(inb);
    if(bal){
      int leader=__ffsll(bal)-1;
      int c2=__popcll(bal);
      int wb=0;
      if(lane==leader) wb=atomicAdd(&wrOff,c2);
      wb=__shfl(wb,leader);
      if(inb){
        int rk=__popcll(bal&((1ull<<lane)-1ull));
        int pos=blkBase+wb+rk;
        if(pos<CAPE) collbuf[pos]=bb;
      }
    }
  }
}

// exact select within bucket (8+8 bit LDS hist), in-bucket min-above, cut
__global__ __launch_bounds__(1024) void k_sel2(const unsigned* __restrict__ collbuf, Scal* sc){
  __shared__ unsigned h[256];
  __shared__ int sel1, below1, sel2, below2, cnt2;
  __shared__ unsigned red[1024];
  int t=threadIdx.x;
  int n=sc->ccount; if(n>CAPE) n=CAPE;
  int r=sc->rank_rem;
  if(t<256) h[t]=0;
  __syncthreads();
  for(int e=t;e<n;e+=1024) atomicAdd(&h[(collbuf[e]>>8)&0xFFu],1u);
  __syncthreads();
  if(t==0){
    int run=0;
    for(int b=0;b<256;b++){ int c=(int)h[b]; if(r<run+c){ sel1=b; below1=run; break; } run+=c; }
  }
  __syncthreads();
  int s1b=sel1;
  int r2=r-below1;
  __syncthreads();
  if(t<256) h[t]=0;
  __syncthreads();
  for(int e=t;e<n;e+=1024){ unsigned bb=collbuf[e]; if(((bb>>8)&0xFFu)==(unsigned)s1b) atomicAdd(&h[bb&0xFFu],1u); }
  __syncthreads();
  if(t==0){
    int run=0;
    for(int b=0;b<256;b++){ int c=(int)h[b]; if(r2<run+c){ sel2=b; below2=run; cnt2=c; break; } run+=c; }
  }
  __syncthreads();
  unsigned vlo=(sc->prefix<<16)|((unsigned)s1b<<8)|(unsigned)sel2;
  unsigned mn=0xFFFFFFFFu;
  for(int e=t;e<n;e+=1024){ unsigned bb=collbuf[e]; if(bb>vlo&&bb<mn) mn=bb; }
  red[t]=mn; __syncthreads();
  for(int o=512;o;o>>=1){ if(t<o){ unsigned ob=red[t+o]; if(ob<red[t]) red[t]=ob; } __syncthreads(); }
  if(t==0){
    unsigned minab=red[0]<sc->minabove?red[0]:sc->minabove;
    int c_le=sc->below_acc+below1+below2+cnt2;
    float slo=__uint_as_float(vlo);
    float shi;
    if(sc->hi==sc->lo) shi=slo;
    else if(c_le>sc->hi) shi=slo;
    else shi=__uint_as_float(minab);
    sc->cut=slo*(1.0f-sc->frac)+shi*sc->frac;
  }
}

// ---------------- post-cut CSR (scan-based, packed edges) ----------------
__global__ __launch_bounds__(256) void k_pc_count(const int* __restrict__ rp, const float* __restrict__ cand, const Scal* __restrict__ sc,
    int* __restrict__ rowcnt, float* __restrict__ cntf){
  int wid=blockIdx.x*4+(threadIdx.x>>6);
  int lane=threadIdx.x&63;
  if(wid>=NN) return;
  int e0=rp[wid], e1=rp[wid+1];
  float cut=sc->cut;
  int c=0;
  for(int e=e0+lane;e<e1;e+=64){ if(e<CAPE && cand[e]>=cut) c++; }
  for(int o=32;o;o>>=1) c+=__shfl_xor(c,o);
  if(lane==0){ rowcnt[wid]=c; cntf[wid]=(float)c; }
}

__global__ __launch_bounds__(256) void k_pc_fill(const int* __restrict__ rp, const int* __restrict__ cols, const float* __restrict__ cand,
    const Scal* __restrict__ sc, const int* __restrict__ rp2, unsigned* __restrict__ epack, float* __restrict__ pval,
    const float* __restrict__ cntf){
  int wid=blockIdx.x*4+(threadIdx.x>>6);
  int lane=threadIdx.x&63;
  if(wid>=NN) return;
  int e0=rp[wid], e1=rp[wid+1];
  float cut=sc->cut, cf=cntf[wid];
  int base=rp2[wid];
  for(int eb=e0;eb<e1;eb+=64){
    int e=eb+lane;
    bool p=(e<e1)&&(e<CAPE)&&(cand[e]>=cut);
    unsigned long long m=__ballot(p);
    if(p){
      int pos=base+__popcll(m&((1ull<<lane)-1ull));
      if(pos<CAPE){ epack[pos]=((unsigned)wid<<12)|(unsigned)cols[e]; pval[pos]=cand[e]/cf; }
    }
    base+=__popcll(m);
  }
}

// ---------------- CC + member lists + chunk table: single block, all in LDS ----------------
__global__ __launch_bounds__(1024) void k_cc(const unsigned* __restrict__ epack, Scal* sc,
    int* __restrict__ labk, int* __restrict__ moff_g, int* __restrict__ memb,
    int* __restrict__ choff_g, int* __restrict__ chm0_g, int* __restrict__ chm1_g){
  __shared__ int lab[NN];
  __shared__ int cnt[NN];
  __shared__ int mof[NN];
  __shared__ int s[1024];
  __shared__ int chg, chg2;
  int t=threadIdx.x;
  for(int i=t;i<NN;i+=1024){ lab[i]=i; cnt[i]=0; }
  int n2=sc->nnz2; if(n2>CAPE) n2=CAPE;
  __syncthreads();
  for(int it=0;it<16;it++){
    if(t==0) chg=0;
    __syncthreads();
    for(int e=t;e<n2;e+=1024){
      unsigned p=epack[e];
      int i=(int)(p>>12), j=(int)(p&4095u);
      if(i<j){
        int li=lab[i], lj=lab[j];
        if(lj<li){ if(atomicMin(&lab[i],lj)>lj) chg=1; }
        else if(li<lj){ if(atomicMin(&lab[j],li)>li) chg=1; }
      }
    }
    __syncthreads();
    for(;;){
      if(t==0) chg2=0;
      __syncthreads();
      int l0=lab[t], l1=lab[t+1024], l2=lab[t+2048];
      int v0=lab[l0], v1=lab[l1], v2=lab[l2];
      __syncthreads();
      if(v0<l0){ lab[t]=v0; chg2=1; }
      if(v1<l1){ lab[t+1024]=v1; chg2=1; }
      if(v2<l2){ lab[t+2048]=v2; chg2=1; }
      __syncthreads();
      if(!chg2) break;
      if(t==0) chg=1;
      __syncthreads();
    }
    if(!chg) break;
    __syncthreads();
  }
  for(int i=t;i<NN;i+=1024){ int l=lab[i]; labk[i]=l; atomicAdd(&cnt[l],1); }
  __syncthreads();
  int a0=cnt[t*3+0], a1=cnt[t*3+1], a2=cnt[t*3+2];
  int loc=a0+a1+a2;
  s[t]=loc; __syncthreads();
  for(int o=1;o<1024;o<<=1){ int v=(t>=o)?s[t-o]:0; __syncthreads(); s[t]+=v; __syncthreads(); }
  int excl=s[t]-loc;
  __syncthreads();
  mof[t*3+0]=excl; mof[t*3+1]=excl+a0; mof[t*3+2]=excl+a0+a1;
  cnt[t*3+0]=excl; cnt[t*3+1]=excl+a0; cnt[t*3+2]=excl+a0+a1;
  moff_g[t*3+0]=excl; moff_g[t*3+1]=excl+a0; moff_g[t*3+2]=excl+a0+a1;
  if(t==1023) moff_g[NN]=s[t];
  __syncthreads();
  int ch0=(a0+63)>>6, ch1=(a1+63)>>6, ch2=(a2+63)>>6;
  int locc=ch0+ch1+ch2;
  s[t]=locc; __syncthreads();
  for(int o=1;o<1024;o<<=1){ int v=(t>=o)?s[t-o]:0; __syncthreads(); s[t]+=v; __syncthreads(); }
  int cexcl=s[t]-locc;
  choff_g[t*3+0]=cexcl; choff_g[t*3+1]=cexcl+ch0; choff_g[t*3+2]=cexcl+ch0+ch1;
  if(t==1023){ choff_g[NN]=s[t]; sc->ncht=s[t]; }
  {
    int bases[3]={cexcl,cexcl+ch0,cexcl+ch0+ch1};
    int cnts[3]={a0,a1,a2};
    int nqs[3]={ch0,ch1,ch2};
    for(int u=0;u<3;u++){
      int m0=mof[t*3+u];
      int me=m0+cnts[u];
      for(int q=0;q<nqs[u];q++){
        int idx=bases[u]+q;
        if(idx<MAXCH){
          chm0_g[idx]=m0+q*64;
          int e2=m0+q*64+64; chm1_g[idx]=e2<me?e2:me;
        }
      }
    }
  }
  __syncthreads();
  int lane=t&63, wv=t>>6;
  for(int b=0;b<3;b++){
    int j=b*1024+t;
    int myl=lab[j];
    int rank_w=0,total=0;
#pragma unroll
    for(int l=0;l<64;l++){
      int lb=__shfl(myl,l);
      if(lb==myl){ total++; if(l<lane) rank_w++; }
    }
    for(int w=0;w<16;w++){
      if(wv==w){
        int base=cnt[myl];
        memb[base+rank_w]=j;
        if(rank_w==0) cnt[myl]=base+total;
      }
      __syncthreads();
    }
  }
}

// ---------------- a2 = C adj C^T: per-block LDS hash (integer-exact), flush to global ----------------
__global__ __launch_bounds__(256) void k_a2e(const int* __restrict__ rowsA, const int* __restrict__ colsA_, const float* __restrict__ aval,
    const Scal* __restrict__ sc, const int* __restrict__ labk, float* __restrict__ dense){
  __shared__ int hkey[HSZ];
  __shared__ unsigned hv[HSZ];
  int t=threadIdx.x;
  for(int i=t;i<HSZ;i+=256){ hkey[i]=-1; hv[i]=0; }
  __syncthreads();
  int n=sc->nnzS; if(n>CAPE) n=CAPE;
  int stride=gridDim.x*256;
  for(int e=blockIdx.x*256+t; e<n; e+=stride){
    float a=aval[e];
    if(a!=0.f){
      int key=labk[rowsA[e]]*NN+labk[colsA_[e]];
      unsigned val=(unsigned)a;
      unsigned hsh=((unsigned)key*2654435761u)&(HSZ-1);
      for(;;){
        int k0=atomicCAS(&hkey[hsh],-1,key);
        if(k0==-1||k0==key){ atomicAdd(&hv[hsh],val); break; }
        hsh=(hsh+1)&(HSZ-1);
      }
    }
  }
  __syncthreads();
  for(int i=t;i<HSZ;i+=256){
    int k0=hkey[i];
    if(k0>=0) atomicAdd(&dense[(size_t)k0],(float)hv[i]);
  }
}

// ---------------- x2: chunked deterministic segmented reduction ----------------
__global__ __launch_bounds__(256) void k_x2p(const float* __restrict__ y, const int* __restrict__ memb,
    const int* __restrict__ chm0, const int* __restrict__ chm1, const Scal* __restrict__ sc, float* __restrict__ partial){
  int b=blockIdx.x;
  if(b>=sc->ncht||b>=MAXCH) return;
  int t=threadIdx.x;
  int m0=chm0[b], m1=chm1[b];
  float acc=0.f;
#pragma unroll 4
  for(int m=m0;m<m1;m++) acc+=y[(size_t)memb[m]*FF+t];
  partial[(size_t)b*FF+t]=acc;
}
__global__ __launch_bounds__(256) void k_x2f(const int* __restrict__ choff, const float* __restrict__ partial, float* __restrict__ out){
  int c=blockIdx.x, t=threadIdx.x;
  int q0=choff[c], q1=choff[c+1];
  float acc=0.f;
  for(int q=q0;q<q1&&q<MAXCH;q++) acc+=partial[(size_t)q*FF+t];
  __shared__ float red[256];
  red[t]=acc*acc; __syncthreads();
  for(int o=128;o;o>>=1){ if(t<o) red[t]+=red[t+o]; __syncthreads(); }
  float nrm=fmaxf(sqrtf(red[0]),1e-12f);
  out[(size_t)c*FF+t]=(q1>q0)?acc/nrm:0.f;
}

__global__ __launch_bounds__(256) void k_final(const int* __restrict__ rp, const int* __restrict__ cols, const float* __restrict__ vals,
    const float* __restrict__ T, const float* __restrict__ bias, float* __restrict__ logp){
  int i=blockIdx.x*256+threadIdx.x;
  if(i>=NN) return;
  float o[16];
#pragma unroll
  for(int f=0;f<16;f++) o[f]=bias[f];
  int e1=rp[i+1];
  for(int e=rp[i];e<e1;e++){
    float v=vals[e]; const float* tr=T+(size_t)cols[e]*16;
#pragma unroll
    for(int f=0;f<16;f++) o[f]+=v*tr[f];
  }
  float m=o[0];
#pragma unroll
  for(int f=1;f<16;f++) m=fmaxf(m,o[f]);
  float ssum=0.f;
#pragma unroll
  for(int f=0;f<16;f++) ssum+=expf(o[f]-m);
  float lse=logf(ssum);
#pragma unroll
  for(int f=0;f<16;f++) logp[(size_t)i*16+f]=o[f]-m-lse;
}

// full-write Cs: CsB[l][c][j] = (labsv[l*NN+j]==c), no memset needed
__global__ __launch_bounds__(256) void k_cs_full(const int* __restrict__ labsv, float* __restrict__ CsB){
  int idx=blockIdx.x*256+threadIdx.x;
  const int ROW4=NN/4;
  int l=idx/(NN*ROW4);
  int rem=idx-l*(NN*ROW4);
  int c=rem/ROW4;
  int j4=(rem-c*ROW4)*4;
  const int* lb=labsv+(size_t)l*NN+j4;
  int4 lv=*(const int4*)lb;
  float4 o;
  o.x=(lv.x==c)?1.0f:0.0f;
  o.y=(lv.y==c)?1.0f:0.0f;
  o.z=(lv.z==c)?1.0f:0.0f;
  o.w=(lv.w==c)?1.0f:0.0f;
  *(float4*)(CsB+(size_t)idx*4)=o;
}

// ================= host =================
extern "C" void kernel_launch(void* const* d_in, const int* in_sizes, int n_in,
                              void* d_out, int out_size, void* d_ws, size_t ws_size,
                              hipStream_t stream) {
  (void)in_sizes; (void)n_in; (void)out_size;
  const float* x_in =(const float*)d_in[0];
  const float* adjC =(const float*)d_in[1];
  const float* adj  =(const float*)d_in[2];
  const float* encW0=(const float*)d_in[3];
  const float* encb0=(const float*)d_in[4];
  const float* encW =(const float*)d_in[5];
  const float* encb =(const float*)d_in[6];
  const float* fcW  =(const float*)d_in[7];
  const float* fcb  =(const float*)d_in[8];
  const float* aW   =(const float*)d_in[9];
  const float* decW =(const float*)d_in[10];
  const float* decb =(const float*)d_in[11];
  const float* decWo=(const float*)d_in[12];
  const float* decbo=(const float*)d_in[13];
  float* out=(float*)d_out;

  float* logp=out;
  float* CsB = out + (size_t)NN*16;
  float* attB= CsB + 3ull*NN*NN;
  float* slot1 = CsB + (size_t)NN*NN;
  float* xs[4]; for(int i=0;i<4;i++) xs[i]=slot1+(size_t)i*NN*FF;
  float* xcur=slot1+(size_t)4*NN*FF;
  float* ybuf=slot1+(size_t)5*NN*FF;
  float* tbuf=slot1+(size_t)6*NN*FF;

  char* w=(char*)d_ws; size_t off=0;
  auto alc=[&](size_t b)->void*{ off=(off+255)&~(size_t)255; void* r=w+off; off+=b; return r; };
  Scal* sc=(Scal*)alc(sizeof(Scal));
  int* rowcnt=(int*)alc((size_t)NN*4);
  int* rp[4]; for(int i=0;i<4;i++) rp[i]=(int*)alc((size_t)(NN+1)*4);
  int* rp2=(int*)alc((size_t)(NN+1)*4);
  int* colsA[4]; float* acv[4];
  for(int i=0;i<4;i++){ colsA[i]=(int*)alc((size_t)CAPE*4); acv[i]=(float*)alc((size_t)CAPE*4); }
  float* avalS=(float*)alc((size_t)CAPE*4);
  int* rowsA=(int*)alc((size_t)CAPE*4);
  float* cand=(float*)alc((size_t)CAPE*4);
  unsigned* collbuf=(unsigned*)alc((size_t)CAPE*4);
  unsigned* epack=(unsigned*)alc((size_t)CAPE*4);
  float* pval=(float*)alc((size_t)CAPE*4);
  unsigned* bins=(unsigned*)alc((size_t)16384*4);
  int* labsv=(int*)alc((size_t)3*NN*4);
  int* moff=(int*)alc((size_t)(NN+1)*4);
  int* memb=(int*)alc((size_t)NN*4);
  int* choff=(int*)alc((size_t)(NN+1)*4);
  int* chm0=(int*)alc((size_t)MAXCH*4);
  int* chm1=(int*)alc((size_t)MAXCH*4);
  float* partial=(float*)alc((size_t)MAXCH*FF*4);
  float* cntf=(float*)alc((size_t)NN*4);
  float* s1=(float*)alc((size_t)NN*4);
  float* s2v=(float*)alc((size_t)NN*4);
  float* Dv=(float*)alc((size_t)NN*4);
  float* t16=(float*)alc((size_t)NN*16*4);
  float* dense;
  size_t denseB=(size_t)NN*NN*4;
  if(ws_size>=off+denseB+4096) dense=(float*)alc(denseB);
  else dense=CsB;

  auto build_csr=[&](const float* Ad, const float* ACd, const float* Dp, int lvl){
    k_count_dense<<<NN,256,0,stream>>>(Ad,rowcnt,Dv);
    k_scan<<<1,1024,0,stream>>>(rowcnt,rp[lvl],&sc->nnzS,sc);
    k_fill_dense<<<NN,256,0,stream>>>(Ad,ACd,Dp,rp[lvl],rowsA,colsA[lvl],avalS,acv[lvl]);
  };

  k_init<<<64,256,0,stream>>>(bins);
  build_csr(adj,adjC,nullptr,0);

  // ---------- encode ----------
  for(int k=0;k<3;k++){
    const float* xin=(k==0)?x_in:xcur;
    const float* Wk=(k==0)?encW0:(encW+(size_t)(k-1)*FF*FF);
    const float* bk=(k==0)?encb0:(encb+(size_t)(k-1)*FF);
    int K=(k==0)?512:FF;
    k_gemm<<<dim3(FF/64,NN/64),256,0,stream>>>(xin,Wk,tbuf,NN,K,FF);
    // fused spmm + edge-score (s1/s2 computed from the normalized output row)
    k_spmm_gcn<<<NN/4,256,0,stream>>>(rp[k],colsA[k],acv[k],tbuf,bk,(k==0)?nullptr:xcur,xs[k],0,
                                      fcW+(size_t)k*FF*64,fcb+(size_t)k*64,aW+(size_t)k*128,s1,s2v);

    k_att_row<<<NN,256,0,stream>>>(rp[k],colsA[k],s1,s2v,attB+(size_t)k*NN*NN,cand,sc);

    // percentile: hist14 -> pick14 -> collect (block-aggregated) -> exact select
    k_hist14<<<64,256,0,stream>>>(cand,sc,bins);
    k_pick14<<<1,256,0,stream>>>(bins,sc);
    k_collect<<<64,256,0,stream>>>(cand,sc,collbuf);
    k_sel2<<<1,1024,0,stream>>>(collbuf,sc);

    // post-cut CSR (scan-based, packed edges)
    k_pc_count<<<NN/4,256,0,stream>>>(rp[k],cand,sc,rowcnt,cntf);
    k_scan<<<1,1024,0,stream>>>(rowcnt,rp2,&sc->nnz2,sc);
    k_pc_fill<<<NN/4,256,0,stream>>>(rp[k],colsA[k],cand,sc,rp2,epack,pval,cntf);

    // CC + member lists + chunk table (one block, packed edges + full shortcut)
    k_cc<<<1,1024,0,stream>>>(epack,sc,labsv+(size_t)k*NN,moff,memb,choff,chm0,chm1);

    // a2 (per-block LDS hash, integer-exact); dense zeroed: memset at level 0, sparse wipe after
    if(k==0) hipMemsetAsync(dense,0,denseB,stream);
    k_a2e<<<256,256,0,stream>>>(rowsA,colsA[k],avalS,sc,labsv+(size_t)k*NN,dense);

    // x2
    k_spmm_plain<<<NN/4,256,0,stream>>>(rp2,epack,pval,xs[k],ybuf);
    k_x2p<<<MAXCH,256,0,stream>>>(ybuf,memb,chm0,chm1,sc,partial);
    k_x2f<<<NN,256,0,stream>>>(choff,partial,xcur);

    build_csr(dense,nullptr,Dv,k+1);
    if(k<2) k_wipe<<<CAPE/256,256,0,stream>>>(rowsA,colsA[k+1],sc,dense);
  }

  // ---------- bottleneck ----------
  k_gemm<<<dim3(FF/64,NN/64),256,0,stream>>>(xcur,encW+(size_t)2*FF*FF,tbuf,NN,FF,FF);
  k_spmm_gcn<<<NN/4,256,0,stream>>>(rp[3],colsA[3],acv[3],tbuf,encb+(size_t)2*FF,nullptr,xs[3],1,
                                    nullptr,nullptr,nullptr,nullptr,nullptr);

  // ---------- decode (fused unpool+concat GEMM) ----------
  float* xd=xs[3];
  float* outsb[3]={xcur,ybuf,xcur};
  for(int k=0;k<3;k++){
    int lev=2-k;
    k_gemm2<<<dim3(FF/64,NN/64),256,0,stream>>>(xd,labsv+(size_t)lev*NN,xs[lev],decW+(size_t)k*512*FF,tbuf);
    k_spmm_gcn<<<NN/4,256,0,stream>>>(rp[lev],colsA[lev],acv[lev],tbuf,decb+(size_t)k*FF,nullptr,outsb[k],1,
                                      nullptr,nullptr,nullptr,nullptr,nullptr);
    xd=outsb[k];
  }

  // ---------- final gcn + log_softmax ----------
  k_gemm16<<<(NN*16)/256,256,0,stream>>>(xd,decWo,t16);
  k_final<<<(NN+255)/256,256,0,stream>>>(rp[0],colsA[0],acv[0],t16,decbo,logp);

  // ---------- materialize Cs (full write, no memset) ----------
  k_cs_full<<<(3*NN*(NN/4))/256,256,0,stream>>>(labsv,CsB);
}